// Round 1
// baseline (1009.766 us; speedup 1.0000x reference)
//
#include <hip/hip_runtime.h>
#include <math.h>

#define Bsz 16
#define Tt 24
#define Nn 256
#define Fp 6
#define Hh 64
#define PredL 12
#define Fw 4
#define G3 192
#define M1 32
#define DEG2RAD 0.017453292519943295f

// ---------------------------------------------------------------------------
// P0: A_c[i][j] = adj[i][j]*cos(ang_ij), A_s = adj*sin(ang_ij)
// ---------------------------------------------------------------------------
__global__ __launch_bounds__(256) void k_prep_ang(
    const float* __restrict__ coords, const float* __restrict__ adj,
    float* __restrict__ Ac, float* __restrict__ As) {
  int i = blockIdx.x;
  int j = threadIdx.x;
  float dx = coords[2 * j]     - coords[2 * i];
  float dy = coords[2 * j + 1] - coords[2 * i + 1];
  float ang = atan2f(dy, dx);           // atan2f(0,0)=0 matches numpy on diag
  float a = adj[i * Nn + j];
  Ac[i * Nn + j] = a * cosf(ang);
  As[i * Nn + j] = a * sinf(ang);
}

// ---------------------------------------------------------------------------
// PT: transpose small weight matrices for coalesced matvec access
// ---------------------------------------------------------------------------
__global__ __launch_bounds__(256) void k_transpose_weights(
    const float* __restrict__ wgc2, const float* __restrict__ wih,
    const float* __restrict__ whh,  const float* __restrict__ wm1,
    const float* __restrict__ wm2,
    float* __restrict__ wgc2T, float* __restrict__ wihT, float* __restrict__ whhT,
    float* __restrict__ wm1T, float* __restrict__ wm2T) {
  int tid = threadIdx.x;
  for (int idx = tid; idx < Hh * Hh; idx += 256) {
    int g = idx / Hh, k = idx % Hh;
    wgc2T[k * Hh + g] = wgc2[g * Hh + k];
  }
  for (int idx = tid; idx < G3 * Hh; idx += 256) {
    int g = idx / Hh, k = idx % Hh;
    wihT[k * G3 + g] = wih[g * Hh + k];
    whhT[k * G3 + g] = whh[g * Hh + k];
  }
  for (int idx = tid; idx < M1 * Hh; idx += 256) {
    int m = idx / Hh, k = idx % Hh;
    wm1T[k * M1 + m] = wm1[m * Hh + k];
  }
  for (int idx = tid; idx < Fp * M1; idx += 256) {
    int f = idx / M1, m = idx % M1;
    wm2T[m * Fp + f] = wm2[f * M1 + m];
  }
}

// ---------------------------------------------------------------------------
// P1: for every (t,b,i): d = 1/(sqrt(rowsum+1)+1e-6), e = 1/(sqrt(colsum+1)+1e-6)
// rowsum_i = sum_j max( s*(Ac[i][j]*cr + As[i][j]*sr), 0)
// colsum_i = sum_j w_out[j][i]; off-diag uses the -val identity, diag uses +val
// ---------------------------------------------------------------------------
__global__ __launch_bounds__(256) void k_deg(
    const float* __restrict__ hw, const float* __restrict__ Ac,
    const float* __restrict__ As,
    float* __restrict__ dbuf, float* __restrict__ ebuf) {
  int t = blockIdx.x / Bsz;
  int b = blockIdx.x % Bsz;
  float spd = hw[(b * Tt + t) * Fw + 2];
  float rad = hw[(b * Tt + t) * Fw + 1] * DEG2RAD;
  float cr = cosf(rad), sr = sinf(rad);
  int w = threadIdx.x >> 6, lane = threadIdx.x & 63;
  for (int m = 0; m < 64; ++m) {
    int i = w * 64 + m;
    float rs = 0.f, cs = 0.f;
#pragma unroll
    for (int c = 0; c < 4; ++c) {
      int j = lane + 64 * c;
      float val = spd * (Ac[i * Nn + j] * cr + As[i * Nn + j] * sr);
      rs += fmaxf(val, 0.f);
      cs += (j == i) ? fmaxf(val, 0.f) : fmaxf(-val, 0.f);
    }
#pragma unroll
    for (int off = 32; off; off >>= 1) {
      rs += __shfl_xor(rs, off);
      cs += __shfl_xor(cs, off);
    }
    if (lane == 0) {
      dbuf[(t * Bsz + b) * Nn + i] = 1.f / (sqrtf(rs + 1.f) + 1e-6f);
      ebuf[(t * Bsz + b) * Nn + i] = 1.f / (sqrtf(cs + 1.f) + 1e-6f);
    }
  }
}

// ---------------------------------------------------------------------------
// K2: gconv1. One wave per output row (b,i).
// y[f] = d_i*( sum_j w_ij*d_j*x[j,f] + d_i*x[i,f] );  h1 = relu(W_gc1 y + b)
// ---------------------------------------------------------------------------
__global__ __launch_bounds__(64) void k_gconv1(
    const float* __restrict__ xbase, int strideB,
    const float* __restrict__ hw, int tw,
    const float* __restrict__ Ac, const float* __restrict__ As,
    const float* __restrict__ dbuf,
    const float* __restrict__ wgc1, const float* __restrict__ bgc1,
    float* __restrict__ h1) {
  __shared__ float d_lds[Nn];
  __shared__ float x_lds[Nn * Fp];
  int b = blockIdx.x / Nn, i = blockIdx.x % Nn;
  int lane = threadIdx.x;
  float spd = hw[(b * Tt + tw) * Fw + 2];
  float rad = hw[(b * Tt + tw) * Fw + 1] * DEG2RAD;
  float cr = cosf(rad), sr = sinf(rad);
  const float* drow = dbuf + (tw * Bsz + b) * Nn;
#pragma unroll
  for (int c = 0; c < 4; ++c) d_lds[lane + 64 * c] = drow[lane + 64 * c];
  const float* xsrc = xbase + (long)b * strideB;
#pragma unroll
  for (int c = 0; c < (Nn * Fp) / 64; ++c) x_lds[lane + 64 * c] = xsrc[lane + 64 * c];
  __syncthreads();
  float acc[Fp] = {0.f, 0.f, 0.f, 0.f, 0.f, 0.f};
#pragma unroll
  for (int c = 0; c < 4; ++c) {
    int j = lane + 64 * c;
    float val = spd * (Ac[i * Nn + j] * cr + As[i * Nn + j] * sr);
    float w = fmaxf(val, 0.f) * d_lds[j];
#pragma unroll
    for (int f = 0; f < Fp; ++f) acc[f] += w * x_lds[j * Fp + f];
  }
#pragma unroll
  for (int f = 0; f < Fp; ++f) {
#pragma unroll
    for (int off = 32; off; off >>= 1) acc[f] += __shfl_xor(acc[f], off);
  }
  float di = d_lds[i];
  float y[Fp];
#pragma unroll
  for (int f = 0; f < Fp; ++f) y[f] = di * (acc[f] + di * x_lds[i * Fp + f]);
  float hv = bgc1[lane];
#pragma unroll
  for (int f = 0; f < Fp; ++f) hv += wgc1[lane * Fp + f] * y[f];
  h1[(b * Nn + i) * Hh + lane] = fmaxf(hv, 0.f);
}

// ---------------------------------------------------------------------------
// K3: gconv2 (transposed adjacency, recomputed on the fly) + W_gc2 transform
//     + GRU, and for the decoder also the output MLP.
// 16 rows per block, 256 threads (4 waves).
// ---------------------------------------------------------------------------
template <int DOMLP>
__global__ __launch_bounds__(256) void k_gconv2_gru(
    const float* __restrict__ hw, int tw,
    const float* __restrict__ Ac, const float* __restrict__ As,
    const float* __restrict__ ebuf, const float* __restrict__ h1,
    const float* __restrict__ wgc2T, const float* __restrict__ bgc2,
    const float* __restrict__ wihT, const float* __restrict__ whhT,
    const float* __restrict__ bih, const float* __restrict__ bhh,
    float* __restrict__ hstate,
    const float* __restrict__ wm1T, const float* __restrict__ bm1,
    const float* __restrict__ wm2T, const float* __restrict__ bm2,
    float* __restrict__ outp, float* __restrict__ xnext, int p) {
  const int IPB = 16;
  __shared__ float e_lds[Nn];
  __shared__ float wv[IPB][Nn];
  __shared__ float red[4][IPB][64];
  __shared__ float y2_lds[IPB][Hh];
  __shared__ float sf_lds[IPB][Hh];
  __shared__ float hp_lds[IPB][Hh];
  __shared__ float hn_lds[IPB][Hh];
  __shared__ float u_lds[IPB][M1];

  int b = blockIdx.x / (Nn / IPB);
  int i0 = (blockIdx.x % (Nn / IPB)) * IPB;
  int tid = threadIdx.x;
  int w = tid >> 6, lane = tid & 63;

  float spd = hw[(b * Tt + tw) * Fw + 2];
  float rad = hw[(b * Tt + tw) * Fw + 1] * DEG2RAD;
  float cr = cosf(rad), sr = sinf(rad);

  e_lds[tid] = ebuf[(tw * Bsz + b) * Nn + tid];
#pragma unroll
  for (int c = 0; c < (IPB * Hh) / 256; ++c) {
    int idx = tid + c * 256;
    hp_lds[idx >> 6][idx & 63] = hstate[(b * Nn + i0) * Hh + idx];
  }
  __syncthreads();

  // wv[r][j] = e_j * w_out[b][j][i0+r]  (+ e_i on the diagonal for the +I term)
#pragma unroll
  for (int r = 0; r < IPB; ++r) {
    int i = i0 + r;
    int j = tid;
    float val = spd * (Ac[i * Nn + j] * cr + As[i * Nn + j] * sr);
    float wt;
    if (j == i)
      wt = fmaxf(val, 0.f) * e_lds[j] + e_lds[j];
    else
      wt = fmaxf(-val, 0.f) * e_lds[j];
    wv[r][j] = wt;
  }
  __syncthreads();

  // aggregation over j: lane = feature h, wave owns a 64-wide j slice
  float acc[IPB];
#pragma unroll
  for (int r = 0; r < IPB; ++r) acc[r] = 0.f;
  const float* h1b = h1 + (long)b * Nn * Hh;
#pragma unroll 4
  for (int jj = 0; jj < 64; ++jj) {
    int j = w * 64 + jj;
    float hv = h1b[j * Hh + lane];
#pragma unroll
    for (int r = 0; r < IPB; ++r) acc[r] += wv[r][j] * hv;
  }
#pragma unroll
  for (int r = 0; r < IPB; ++r) red[w][r][lane] = acc[r];
  __syncthreads();

  // cross-wave reduce; wave w owns rows w*4..w*4+3 from here on
#pragma unroll
  for (int rr = 0; rr < 4; ++rr) {
    int r = w * 4 + rr;
    float v = red[0][r][lane] + red[1][r][lane] + red[2][r][lane] + red[3][r][lane];
    y2_lds[r][lane] = v * e_lds[i0 + r];
  }
  // sf = relu(W_gc2 y2 + b_gc2)   (wave-local: wave w wrote y2 rows w*4..w*4+3)
  {
    float a0 = bgc2[lane], a1 = a0, a2 = a0, a3 = a0;
    for (int k = 0; k < Hh; ++k) {
      float wk = wgc2T[k * Hh + lane];
      a0 += wk * y2_lds[w * 4 + 0][k];
      a1 += wk * y2_lds[w * 4 + 1][k];
      a2 += wk * y2_lds[w * 4 + 2][k];
      a3 += wk * y2_lds[w * 4 + 3][k];
    }
    sf_lds[w * 4 + 0][lane] = fmaxf(a0, 0.f);
    sf_lds[w * 4 + 1][lane] = fmaxf(a1, 0.f);
    sf_lds[w * 4 + 2][lane] = fmaxf(a2, 0.f);
    sf_lds[w * 4 + 3][lane] = fmaxf(a3, 0.f);
  }

  // GRU for rows w*4..w*4+3 (register-blocked over 4 rows per thread)
  {
    float gir[4], giz[4], gin[4], ghr[4], ghz[4], ghn[4];
#pragma unroll
    for (int r = 0; r < 4; ++r) {
      gir[r] = bih[lane];
      giz[r] = bih[64 + lane];
      gin[r] = bih[128 + lane];
      ghr[r] = bhh[lane];
      ghz[r] = bhh[64 + lane];
      ghn[r] = bhh[128 + lane];
    }
    for (int k = 0; k < Hh; ++k) {
      float wir = wihT[k * G3 + lane];
      float wiz = wihT[k * G3 + 64 + lane];
      float win = wihT[k * G3 + 128 + lane];
      float whr = whhT[k * G3 + lane];
      float whz = whhT[k * G3 + 64 + lane];
      float whn = whhT[k * G3 + 128 + lane];
#pragma unroll
      for (int r = 0; r < 4; ++r) {
        float sfk = sf_lds[w * 4 + r][k];
        float hk = hp_lds[w * 4 + r][k];
        gir[r] += wir * sfk;
        giz[r] += wiz * sfk;
        gin[r] += win * sfk;
        ghr[r] += whr * hk;
        ghz[r] += whz * hk;
        ghn[r] += whn * hk;
      }
    }
#pragma unroll
    for (int r = 0; r < 4; ++r) {
      int row = w * 4 + r;
      float rg = 1.f / (1.f + expf(-(gir[r] + ghr[r])));
      float zg = 1.f / (1.f + expf(-(giz[r] + ghz[r])));
      float ng = tanhf(gin[r] + rg * ghn[r]);
      float hn = (1.f - zg) * ng + zg * hp_lds[row][lane];
      hstate[(b * Nn + i0 + row) * Hh + lane] = hn;
      if (DOMLP) hn_lds[row][lane] = hn;
    }
  }

  if (DOMLP) {
    __syncthreads();
#pragma unroll
    for (int rep = 0; rep < 2; ++rep) {
      int idx = tid + rep * 256;
      int row = idx >> 5, m = idx & 31;
      float um = bm1[m];
      for (int k = 0; k < Hh; ++k) um += wm1T[k * M1 + m] * hn_lds[row][k];
      u_lds[row][m] = fmaxf(um, 0.f);
    }
    __syncthreads();
    if (tid < IPB * Fp) {
      int row = tid / Fp, f = tid % Fp;
      float pf = bm2[f];
#pragma unroll
      for (int m = 0; m < M1; ++m) pf += wm2T[m * Fp + f] * u_lds[row][m];
      int i = i0 + row;
      outp[((b * PredL + p) * Nn + i) * Fp + f] = pf;
      xnext[(b * Nn + i) * Fp + f] = pf;
    }
  }
}

// ---------------------------------------------------------------------------
// dec0: x0 = mlp(h) for all B*N rows
// ---------------------------------------------------------------------------
__global__ __launch_bounds__(256) void k_dec0(
    const float* __restrict__ hstate,
    const float* __restrict__ wm1T, const float* __restrict__ bm1,
    const float* __restrict__ wm2T, const float* __restrict__ bm2,
    float* __restrict__ xnext) {
  const int RPB = 16;
  __shared__ float h_lds[RPB][Hh];
  __shared__ float u_lds[RPB][M1];
  int r0 = blockIdx.x * RPB;
  int tid = threadIdx.x;
#pragma unroll
  for (int c = 0; c < (RPB * Hh) / 256; ++c) {
    int idx = tid + c * 256;
    h_lds[idx >> 6][idx & 63] = hstate[r0 * Hh + idx];
  }
  __syncthreads();
#pragma unroll
  for (int rep = 0; rep < 2; ++rep) {
    int idx = tid + rep * 256;
    int row = idx >> 5, m = idx & 31;
    float um = bm1[m];
    for (int k = 0; k < Hh; ++k) um += wm1T[k * M1 + m] * h_lds[row][k];
    u_lds[row][m] = fmaxf(um, 0.f);
  }
  __syncthreads();
  if (tid < RPB * Fp) {
    int row = tid / Fp, f = tid % Fp;
    float pf = bm2[f];
#pragma unroll
    for (int m = 0; m < M1; ++m) pf += wm2T[m * Fp + f] * u_lds[row][m];
    xnext[(r0 + row) * Fp + f] = pf;
  }
}

// ---------------------------------------------------------------------------
extern "C" void kernel_launch(void* const* d_in, const int* in_sizes, int n_in,
                              void* d_out, int out_size, void* d_ws, size_t ws_size,
                              hipStream_t stream) {
  const float* hp     = (const float*)d_in[0];
  const float* hw     = (const float*)d_in[1];
  const float* adj    = (const float*)d_in[2];
  const float* coords = (const float*)d_in[3];
  const float* wgc1   = (const float*)d_in[4];
  const float* bgc1   = (const float*)d_in[5];
  const float* wgc2   = (const float*)d_in[6];
  const float* bgc2   = (const float*)d_in[7];
  const float* wih    = (const float*)d_in[8];
  const float* whh    = (const float*)d_in[9];
  const float* bih    = (const float*)d_in[10];
  const float* bhh    = (const float*)d_in[11];
  const float* wm1    = (const float*)d_in[12];
  const float* bm1    = (const float*)d_in[13];
  const float* wm2    = (const float*)d_in[14];
  const float* bm2    = (const float*)d_in[15];
  float* out = (float*)d_out;

  float* w = (float*)d_ws;
  float* Ac     = w; w += Nn * Nn;
  float* As     = w; w += Nn * Nn;
  float* dbuf   = w; w += Tt * Bsz * Nn;
  float* ebuf   = w; w += Tt * Bsz * Nn;
  float* hstate = w; w += Bsz * Nn * Hh;
  float* h1     = w; w += Bsz * Nn * Hh;
  float* xb     = w; w += Bsz * Nn * Fp;
  float* wgc2T  = w; w += Hh * Hh;
  float* wihT   = w; w += Hh * G3;
  float* whhT   = w; w += Hh * G3;
  float* wm1T   = w; w += Hh * M1;
  float* wm2T   = w; w += M1 * Fp;

  hipMemsetAsync(hstate, 0, Bsz * Nn * Hh * sizeof(float), stream);

  k_prep_ang<<<Nn, 256, 0, stream>>>(coords, adj, Ac, As);
  k_transpose_weights<<<1, 256, 0, stream>>>(wgc2, wih, whh, wm1, wm2,
                                             wgc2T, wihT, whhT, wm1T, wm2T);
  k_deg<<<Tt * Bsz, 256, 0, stream>>>(hw, Ac, As, dbuf, ebuf);

  for (int t = 0; t < Tt; ++t) {
    k_gconv1<<<Bsz * Nn, 64, 0, stream>>>(hp + t * Nn * Fp, Tt * Nn * Fp, hw, t,
                                          Ac, As, dbuf, wgc1, bgc1, h1);
    k_gconv2_gru<0><<<Bsz * (Nn / 16), 256, 0, stream>>>(
        hw, t, Ac, As, ebuf, h1, wgc2T, bgc2, wihT, whhT, bih, bhh, hstate,
        wm1T, bm1, wm2T, bm2, out, xb, 0);
  }

  k_dec0<<<Bsz * Nn / 16, 256, 0, stream>>>(hstate, wm1T, bm1, wm2T, bm2, xb);

  for (int p = 0; p < PredL; ++p) {
    k_gconv1<<<Bsz * Nn, 64, 0, stream>>>(xb, Nn * Fp, hw, Tt - 1,
                                          Ac, As, dbuf, wgc1, bgc1, h1);
    k_gconv2_gru<1><<<Bsz * (Nn / 16), 256, 0, stream>>>(
        hw, Tt - 1, Ac, As, ebuf, h1, wgc2T, bgc2, wihT, whhT, bih, bhh, hstate,
        wm1T, bm1, wm2T, bm2, out, xb, p);
  }
}

// Round 2
// 769.372 us; speedup vs baseline: 1.3125x; 1.3125x over previous
//
#include <hip/hip_runtime.h>
#include <math.h>

#define Bsz 16
#define Tt 24
#define Nn 256
#define Fp 6
#define Hh 64
#define PredL 12
#define Fw 4
#define G3 192
#define M1 32
#define DEG2RAD 0.017453292519943295f
#define IDX2(t, b) ((t) * Bsz + (b))

// ---------------------------------------------------------------------------
// P0: A_c[i][j] = adj[i][j]*cos(ang_ij), A_s = adj*sin(ang_ij)
// ---------------------------------------------------------------------------
__global__ __launch_bounds__(256) void k_prep_ang(
    const float* __restrict__ coords, const float* __restrict__ adj,
    float* __restrict__ Ac, float* __restrict__ As) {
  int i = blockIdx.x;
  int j = threadIdx.x;
  float dx = coords[2 * j]     - coords[2 * i];
  float dy = coords[2 * j + 1] - coords[2 * i + 1];
  float ang = atan2f(dy, dx);
  float a = adj[i * Nn + j];
  Ac[i * Nn + j] = a * cosf(ang);
  As[i * Nn + j] = a * sinf(ang);
}

// ---------------------------------------------------------------------------
// PT: transpose small weight matrices
// ---------------------------------------------------------------------------
__global__ __launch_bounds__(256) void k_transpose_weights(
    const float* __restrict__ wgc2, const float* __restrict__ wih,
    const float* __restrict__ whh,  const float* __restrict__ wm1,
    const float* __restrict__ wm2,
    float* __restrict__ wgc2T, float* __restrict__ wihT, float* __restrict__ whhT,
    float* __restrict__ wm1T, float* __restrict__ wm2T) {
  int tid = threadIdx.x;
  for (int idx = tid; idx < Hh * Hh; idx += 256) {
    int g = idx / Hh, k = idx % Hh;
    wgc2T[k * Hh + g] = wgc2[g * Hh + k];
  }
  for (int idx = tid; idx < G3 * Hh; idx += 256) {
    int g = idx / Hh, k = idx % Hh;
    wihT[k * G3 + g] = wih[g * Hh + k];
    whhT[k * G3 + g] = whh[g * Hh + k];
  }
  for (int idx = tid; idx < M1 * Hh; idx += 256) {
    int m = idx / Hh, k = idx % Hh;
    wm1T[k * M1 + m] = wm1[m * Hh + k];
  }
  for (int idx = tid; idx < Fp * M1; idx += 256) {
    int f = idx / M1, m = idx % M1;
    wm2T[m * Fp + f] = wm2[f * M1 + m];
  }
}

// ---------------------------------------------------------------------------
// P1: degree normalizations for every (t,b,i). 4 blocks per (t,b), each wave
// handles 16 rows.
// ---------------------------------------------------------------------------
__global__ __launch_bounds__(256) void k_deg(
    const float* __restrict__ hw, const float* __restrict__ Ac,
    const float* __restrict__ As,
    float* __restrict__ dbuf, float* __restrict__ ebuf) {
  int q  = blockIdx.x & 3;
  int tb = blockIdx.x >> 2;
  int t = tb / Bsz, b = tb % Bsz;
  float spd = hw[(b * Tt + t) * Fw + 2];
  float rad = hw[(b * Tt + t) * Fw + 1] * DEG2RAD;
  float cr = cosf(rad), sr = sinf(rad);
  int w = threadIdx.x >> 6, lane = threadIdx.x & 63;
  for (int m = 0; m < 16; ++m) {
    int i = q * 64 + w * 16 + m;
    float rs = 0.f, cs = 0.f;
#pragma unroll
    for (int c = 0; c < 4; ++c) {
      int j = lane + 64 * c;
      float val = spd * (Ac[i * Nn + j] * cr + As[i * Nn + j] * sr);
      rs += fmaxf(val, 0.f);
      cs += (j == i) ? fmaxf(val, 0.f) : fmaxf(-val, 0.f);
    }
#pragma unroll
    for (int off = 32; off; off >>= 1) {
      rs += __shfl_xor(rs, off);
      cs += __shfl_xor(cs, off);
    }
    if (lane == 0) {
      dbuf[IDX2(t, b) * Nn + i] = 1.f / (sqrtf(rs + 1.f) + 1e-6f);
      ebuf[IDX2(t, b) * Nn + i] = 1.f / (sqrtf(cs + 1.f) + 1e-6f);
    }
  }
}

// ---------------------------------------------------------------------------
// E1: batched encoder gconv1 over ALL t. 16 rows/block, wave handles 4 rows.
// ---------------------------------------------------------------------------
__global__ __launch_bounds__(256) void k_gconv1_enc(
    const float* __restrict__ hp, const float* __restrict__ hw,
    const float* __restrict__ Ac, const float* __restrict__ As,
    const float* __restrict__ dbuf,
    const float* __restrict__ wgc1, const float* __restrict__ bgc1,
    float* __restrict__ h1_all) {
  __shared__ float d_lds[Nn];
  __shared__ float x_lds[Nn * Fp];
  int ig = blockIdx.x & 15;
  int tb = blockIdx.x >> 4;
  int t = tb / Bsz, b = tb % Bsz;
  int i0 = ig * 16;
  int tid = threadIdx.x, w = tid >> 6, lane = tid & 63;
  float spd = hw[(b * Tt + t) * Fw + 2];
  float rad = hw[(b * Tt + t) * Fw + 1] * DEG2RAD;
  float cr = cosf(rad), sr = sinf(rad);
  d_lds[tid] = dbuf[IDX2(t, b) * Nn + tid];
  const float* xsrc = hp + (long)(b * Tt + t) * Nn * Fp;
#pragma unroll
  for (int c = 0; c < 6; ++c) x_lds[tid + 256 * c] = xsrc[tid + 256 * c];
  __syncthreads();
#pragma unroll
  for (int rr = 0; rr < 4; ++rr) {
    int i = i0 + w * 4 + rr;
    float acc[Fp] = {0.f, 0.f, 0.f, 0.f, 0.f, 0.f};
#pragma unroll
    for (int c = 0; c < 4; ++c) {
      int j = lane + 64 * c;
      float val = spd * (Ac[i * Nn + j] * cr + As[i * Nn + j] * sr);
      float wt = fmaxf(val, 0.f) * d_lds[j];
#pragma unroll
      for (int f = 0; f < Fp; ++f) acc[f] += wt * x_lds[j * Fp + f];
    }
#pragma unroll
    for (int f = 0; f < Fp; ++f) {
#pragma unroll
      for (int off = 32; off; off >>= 1) acc[f] += __shfl_xor(acc[f], off);
    }
    float di = d_lds[i];
    float y[Fp];
#pragma unroll
    for (int f = 0; f < Fp; ++f) y[f] = di * (acc[f] + di * x_lds[i * Fp + f]);
    float hv = bgc1[lane];
#pragma unroll
    for (int f = 0; f < Fp; ++f) hv += wgc1[lane * Fp + f] * y[f];
    h1_all[((long)IDX2(t, b) * Nn + i) * Hh + lane] = fmaxf(hv, 0.f);
  }
}

// ---------------------------------------------------------------------------
// E2: batched encoder gconv2 + W_gc2 transform over ALL t -> sf_all
// ---------------------------------------------------------------------------
__global__ __launch_bounds__(256) void k_gconv2_enc(
    const float* __restrict__ hw, const float* __restrict__ Ac,
    const float* __restrict__ As, const float* __restrict__ ebuf,
    const float* __restrict__ h1_all,
    const float* __restrict__ wgc2T, const float* __restrict__ bgc2,
    float* __restrict__ sf_all) {
  __shared__ float e_lds[Nn];
  __shared__ __align__(16) float wvT[Nn * 20];
  __shared__ float red[4][16][Hh];
  __shared__ float y2[16][Hh];
  int ig = blockIdx.x & 15;
  int tb = blockIdx.x >> 4;
  int t = tb / Bsz, b = tb % Bsz;
  int i0 = ig * 16;
  int tid = threadIdx.x, w = tid >> 6, lane = tid & 63;
  float spd = hw[(b * Tt + t) * Fw + 2];
  float rad = hw[(b * Tt + t) * Fw + 1] * DEG2RAD;
  float cr = cosf(rad), sr = sinf(rad);
  e_lds[tid] = ebuf[IDX2(t, b) * Nn + tid];
  __syncthreads();
  float ej = e_lds[tid];
#pragma unroll
  for (int r = 0; r < 16; ++r) {
    int i = i0 + r;
    int j = tid;
    float val = spd * (Ac[i * Nn + j] * cr + As[i * Nn + j] * sr);
    float wt = (j == i) ? (fmaxf(val, 0.f) * ej + ej) : (fmaxf(-val, 0.f) * ej);
    wvT[j * 20 + r] = wt;
  }
  __syncthreads();
  float acc[16];
#pragma unroll
  for (int r = 0; r < 16; ++r) acc[r] = 0.f;
  const float* h1b = h1_all + (long)IDX2(t, b) * Nn * Hh;
#pragma unroll 4
  for (int jj = 0; jj < 64; ++jj) {
    int j = w * 64 + jj;
    float hv = h1b[j * Hh + lane];
    const float4* wp = (const float4*)(wvT + j * 20);
    float4 w0 = wp[0], w1 = wp[1], w2 = wp[2], w3 = wp[3];
    acc[0] += w0.x * hv; acc[1] += w0.y * hv; acc[2] += w0.z * hv; acc[3] += w0.w * hv;
    acc[4] += w1.x * hv; acc[5] += w1.y * hv; acc[6] += w1.z * hv; acc[7] += w1.w * hv;
    acc[8] += w2.x * hv; acc[9] += w2.y * hv; acc[10] += w2.z * hv; acc[11] += w2.w * hv;
    acc[12] += w3.x * hv; acc[13] += w3.y * hv; acc[14] += w3.z * hv; acc[15] += w3.w * hv;
  }
#pragma unroll
  for (int r = 0; r < 16; ++r) red[w][r][lane] = acc[r];
  __syncthreads();
#pragma unroll
  for (int rr = 0; rr < 4; ++rr) {
    int r = w * 4 + rr;
    float v = red[0][r][lane] + red[1][r][lane] + red[2][r][lane] + red[3][r][lane];
    y2[r][lane] = v * e_lds[i0 + r];
  }
  float a0 = bgc2[lane], a1 = a0, a2 = a0, a3 = a0;
  for (int k = 0; k < Hh; ++k) {
    float wk = wgc2T[k * Hh + lane];
    a0 += wk * y2[w * 4 + 0][k];
    a1 += wk * y2[w * 4 + 1][k];
    a2 += wk * y2[w * 4 + 2][k];
    a3 += wk * y2[w * 4 + 3][k];
  }
  long base = ((long)IDX2(t, b) * Nn + i0 + w * 4) * Hh + lane;
  sf_all[base + 0 * Hh] = fmaxf(a0, 0.f);
  sf_all[base + 1 * Hh] = fmaxf(a1, 0.f);
  sf_all[base + 2 * Hh] = fmaxf(a2, 0.f);
  sf_all[base + 3 * Hh] = fmaxf(a3, 0.f);
}

// ---------------------------------------------------------------------------
// E3: GRU scan over 24 encoder steps. Weights in LDS (96KB), h in registers,
// cross-lane values via __shfl. No per-step barriers.
// ---------------------------------------------------------------------------
__global__ __launch_bounds__(256) void k_gru_scan(
    const float* __restrict__ sf_all,
    const float* __restrict__ wihT, const float* __restrict__ whhT,
    const float* __restrict__ bih, const float* __restrict__ bhh,
    float* __restrict__ hstate) {
  __shared__ float wih_s[Hh * G3];
  __shared__ float whh_s[Hh * G3];
  int b = blockIdx.x >> 4;
  int i0 = (blockIdx.x & 15) * 16;
  int tid = threadIdx.x, w = tid >> 6, lane = tid & 63;
  for (int idx = tid; idx < Hh * G3; idx += 256) {
    wih_s[idx] = wihT[idx];
    whh_s[idx] = whhT[idx];
  }
  __syncthreads();
  float bi_r = bih[lane], bi_z = bih[64 + lane], bi_n = bih[128 + lane];
  float bh_r = bhh[lane], bh_z = bhh[64 + lane], bh_n = bhh[128 + lane];
  float h_reg[4] = {0.f, 0.f, 0.f, 0.f};
  for (int t = 0; t < Tt; ++t) {
    float sf_reg[4];
#pragma unroll
    for (int rr = 0; rr < 4; ++rr)
      sf_reg[rr] = sf_all[((long)IDX2(t, b) * Nn + i0 + w * 4 + rr) * Hh + lane];
    float gir[4], giz[4], gin[4], ghr[4], ghz[4], ghn[4];
#pragma unroll
    for (int rr = 0; rr < 4; ++rr) {
      gir[rr] = bi_r; giz[rr] = bi_z; gin[rr] = bi_n;
      ghr[rr] = bh_r; ghz[rr] = bh_z; ghn[rr] = bh_n;
    }
#pragma unroll 4
    for (int k = 0; k < Hh; ++k) {
      float wir = wih_s[k * G3 + lane];
      float wiz = wih_s[k * G3 + 64 + lane];
      float win = wih_s[k * G3 + 128 + lane];
      float whr = whh_s[k * G3 + lane];
      float whz = whh_s[k * G3 + 64 + lane];
      float whn = whh_s[k * G3 + 128 + lane];
#pragma unroll
      for (int rr = 0; rr < 4; ++rr) {
        float sfk = __shfl(sf_reg[rr], k);
        float hk  = __shfl(h_reg[rr], k);
        gir[rr] += wir * sfk;
        giz[rr] += wiz * sfk;
        gin[rr] += win * sfk;
        ghr[rr] += whr * hk;
        ghz[rr] += whz * hk;
        ghn[rr] += whn * hk;
      }
    }
#pragma unroll
    for (int rr = 0; rr < 4; ++rr) {
      float rg = 1.f / (1.f + expf(-(gir[rr] + ghr[rr])));
      float zg = 1.f / (1.f + expf(-(giz[rr] + ghz[rr])));
      float ng = tanhf(gin[rr] + rg * ghn[rr]);
      h_reg[rr] = (1.f - zg) * ng + zg * h_reg[rr];
    }
  }
#pragma unroll
  for (int rr = 0; rr < 4; ++rr)
    hstate[((long)b * Nn + i0 + w * 4 + rr) * Hh + lane] = h_reg[rr];
}

// ---------------------------------------------------------------------------
// D0: materialize decoder normalized adjacencies (t = Tt-1), both directions.
// ---------------------------------------------------------------------------
__global__ __launch_bounds__(256) void k_norm_dec(
    const float* __restrict__ hw, const float* __restrict__ Ac,
    const float* __restrict__ As,
    const float* __restrict__ dbuf, const float* __restrict__ ebuf,
    float* __restrict__ A1d, float* __restrict__ A2d) {
  int b = blockIdx.x >> 8;
  int i = blockIdx.x & 255;
  int j = threadIdx.x;
  float spd = hw[(b * Tt + (Tt - 1)) * Fw + 2];
  float rad = hw[(b * Tt + (Tt - 1)) * Fw + 1] * DEG2RAD;
  float cr = cosf(rad), sr = sinf(rad);
  const float* drow = dbuf + IDX2(Tt - 1, b) * Nn;
  const float* erow = ebuf + IDX2(Tt - 1, b) * Nn;
  float val = spd * (Ac[i * Nn + j] * cr + As[i * Nn + j] * sr);
  float wout = fmaxf(val, 0.f);
  float win  = (j == i) ? wout : fmaxf(-val, 0.f);
  float dlt = (j == i) ? 1.f : 0.f;
  A1d[((long)b * Nn + i) * Nn + j] = drow[i] * (wout + dlt) * drow[j];
  A2d[((long)b * Nn + i) * Nn + j] = erow[i] * (win + dlt) * erow[j];
}

// ---------------------------------------------------------------------------
// Ddec: gconv1 for decoder (precomputed A1d)
// ---------------------------------------------------------------------------
__global__ __launch_bounds__(256) void k_gconv1_dec(
    const float* __restrict__ xb, const float* __restrict__ A1d,
    const float* __restrict__ wgc1, const float* __restrict__ bgc1,
    float* __restrict__ h1d) {
  __shared__ float x_lds[Nn * Fp];
  int b = blockIdx.x >> 4;
  int i0 = (blockIdx.x & 15) * 16;
  int tid = threadIdx.x, w = tid >> 6, lane = tid & 63;
  const float* xsrc = xb + (long)b * Nn * Fp;
#pragma unroll
  for (int c = 0; c < 6; ++c) x_lds[tid + 256 * c] = xsrc[tid + 256 * c];
  __syncthreads();
#pragma unroll
  for (int rr = 0; rr < 4; ++rr) {
    int i = i0 + w * 4 + rr;
    const float* arow = A1d + ((long)b * Nn + i) * Nn;
    float acc[Fp] = {0.f, 0.f, 0.f, 0.f, 0.f, 0.f};
#pragma unroll
    for (int c = 0; c < 4; ++c) {
      int j = lane + 64 * c;
      float wt = arow[j];
#pragma unroll
      for (int f = 0; f < Fp; ++f) acc[f] += wt * x_lds[j * Fp + f];
    }
#pragma unroll
    for (int f = 0; f < Fp; ++f) {
#pragma unroll
      for (int off = 32; off; off >>= 1) acc[f] += __shfl_xor(acc[f], off);
    }
    float hv = bgc1[lane];
#pragma unroll
    for (int f = 0; f < Fp; ++f) hv += wgc1[lane * Fp + f] * acc[f];
    h1d[((long)b * Nn + i) * Hh + lane] = fmaxf(hv, 0.f);
  }
}

// ---------------------------------------------------------------------------
// Ddec2: decoder gconv2 + GRU + MLP. Weights LDS-cached, sf/h in registers.
// ---------------------------------------------------------------------------
__global__ __launch_bounds__(256) void k_gconv2_gru_dec(
    const float* __restrict__ A2d, const float* __restrict__ h1d,
    const float* __restrict__ wgc2T, const float* __restrict__ bgc2,
    const float* __restrict__ wihT, const float* __restrict__ whhT,
    const float* __restrict__ bih, const float* __restrict__ bhh,
    float* __restrict__ hstate,
    const float* __restrict__ wm1T, const float* __restrict__ bm1,
    const float* __restrict__ wm2T, const float* __restrict__ bm2,
    float* __restrict__ outp, float* __restrict__ xnext, int p) {
  __shared__ __align__(16) float wvT[Nn * 20];
  __shared__ float red[4][16][Hh];
  __shared__ float y2[16][Hh];
  __shared__ float hn_lds[16][Hh];
  __shared__ float u_lds[16][M1];
  __shared__ float wih_s[Hh * G3];
  __shared__ float whh_s[Hh * G3];
  int b = blockIdx.x >> 4;
  int i0 = (blockIdx.x & 15) * 16;
  int tid = threadIdx.x, w = tid >> 6, lane = tid & 63;

  for (int idx = tid; idx < Hh * G3; idx += 256) {
    wih_s[idx] = wihT[idx];
    whh_s[idx] = whhT[idx];
  }
#pragma unroll
  for (int r = 0; r < 16; ++r)
    wvT[tid * 20 + r] = A2d[((long)b * Nn + i0 + r) * Nn + tid];
  float hp_reg[4];
#pragma unroll
  for (int rr = 0; rr < 4; ++rr)
    hp_reg[rr] = hstate[((long)b * Nn + i0 + w * 4 + rr) * Hh + lane];
  __syncthreads();

  float acc[16];
#pragma unroll
  for (int r = 0; r < 16; ++r) acc[r] = 0.f;
  const float* h1b = h1d + (long)b * Nn * Hh;
#pragma unroll 4
  for (int jj = 0; jj < 64; ++jj) {
    int j = w * 64 + jj;
    float hv = h1b[j * Hh + lane];
    const float4* wp = (const float4*)(wvT + j * 20);
    float4 w0 = wp[0], w1 = wp[1], w2 = wp[2], w3 = wp[3];
    acc[0] += w0.x * hv; acc[1] += w0.y * hv; acc[2] += w0.z * hv; acc[3] += w0.w * hv;
    acc[4] += w1.x * hv; acc[5] += w1.y * hv; acc[6] += w1.z * hv; acc[7] += w1.w * hv;
    acc[8] += w2.x * hv; acc[9] += w2.y * hv; acc[10] += w2.z * hv; acc[11] += w2.w * hv;
    acc[12] += w3.x * hv; acc[13] += w3.y * hv; acc[14] += w3.z * hv; acc[15] += w3.w * hv;
  }
#pragma unroll
  for (int r = 0; r < 16; ++r) red[w][r][lane] = acc[r];
  __syncthreads();
#pragma unroll
  for (int rr = 0; rr < 4; ++rr) {
    int r = w * 4 + rr;
    y2[r][lane] = red[0][r][lane] + red[1][r][lane] + red[2][r][lane] + red[3][r][lane];
  }
  float a0 = bgc2[lane], a1 = a0, a2 = a0, a3 = a0;
  for (int k = 0; k < Hh; ++k) {
    float wk = wgc2T[k * Hh + lane];
    a0 += wk * y2[w * 4 + 0][k];
    a1 += wk * y2[w * 4 + 1][k];
    a2 += wk * y2[w * 4 + 2][k];
    a3 += wk * y2[w * 4 + 3][k];
  }
  float sf_reg[4];
  sf_reg[0] = fmaxf(a0, 0.f);
  sf_reg[1] = fmaxf(a1, 0.f);
  sf_reg[2] = fmaxf(a2, 0.f);
  sf_reg[3] = fmaxf(a3, 0.f);

  float gir[4], giz[4], gin[4], ghr[4], ghz[4], ghn[4];
#pragma unroll
  for (int rr = 0; rr < 4; ++rr) {
    gir[rr] = bih[lane]; giz[rr] = bih[64 + lane]; gin[rr] = bih[128 + lane];
    ghr[rr] = bhh[lane]; ghz[rr] = bhh[64 + lane]; ghn[rr] = bhh[128 + lane];
  }
#pragma unroll 4
  for (int k = 0; k < Hh; ++k) {
    float wir = wih_s[k * G3 + lane];
    float wiz = wih_s[k * G3 + 64 + lane];
    float win = wih_s[k * G3 + 128 + lane];
    float whr = whh_s[k * G3 + lane];
    float whz = whh_s[k * G3 + 64 + lane];
    float whn = whh_s[k * G3 + 128 + lane];
#pragma unroll
    for (int rr = 0; rr < 4; ++rr) {
      float sfk = __shfl(sf_reg[rr], k);
      float hk  = __shfl(hp_reg[rr], k);
      gir[rr] += wir * sfk;
      giz[rr] += wiz * sfk;
      gin[rr] += win * sfk;
      ghr[rr] += whr * hk;
      ghz[rr] += whz * hk;
      ghn[rr] += whn * hk;
    }
  }
#pragma unroll
  for (int rr = 0; rr < 4; ++rr) {
    int row = w * 4 + rr;
    float rg = 1.f / (1.f + expf(-(gir[rr] + ghr[rr])));
    float zg = 1.f / (1.f + expf(-(giz[rr] + ghz[rr])));
    float ng = tanhf(gin[rr] + rg * ghn[rr]);
    float hn = (1.f - zg) * ng + zg * hp_reg[rr];
    hstate[((long)b * Nn + i0 + row) * Hh + lane] = hn;
    hn_lds[row][lane] = hn;
  }
  __syncthreads();
#pragma unroll
  for (int rep = 0; rep < 2; ++rep) {
    int idx = tid + rep * 256;
    int row = idx >> 5, m = idx & 31;
    float um = bm1[m];
    for (int k = 0; k < Hh; ++k) um += wm1T[k * M1 + m] * hn_lds[row][k];
    u_lds[row][m] = fmaxf(um, 0.f);
  }
  __syncthreads();
  if (tid < 16 * Fp) {
    int row = tid / Fp, f = tid % Fp;
    float pf = bm2[f];
#pragma unroll
    for (int m = 0; m < M1; ++m) pf += wm2T[m * Fp + f] * u_lds[row][m];
    int i = i0 + row;
    outp[(((long)b * PredL + p) * Nn + i) * Fp + f] = pf;
    xnext[((long)b * Nn + i) * Fp + f] = pf;
  }
}

// ---------------------------------------------------------------------------
// dec0: x0 = mlp(h) for all B*N rows
// ---------------------------------------------------------------------------
__global__ __launch_bounds__(256) void k_dec0(
    const float* __restrict__ hstate,
    const float* __restrict__ wm1T, const float* __restrict__ bm1,
    const float* __restrict__ wm2T, const float* __restrict__ bm2,
    float* __restrict__ xnext) {
  const int RPB = 16;
  __shared__ float h_lds[RPB][Hh];
  __shared__ float u_lds[RPB][M1];
  int r0 = blockIdx.x * RPB;
  int tid = threadIdx.x;
#pragma unroll
  for (int c = 0; c < (RPB * Hh) / 256; ++c) {
    int idx = tid + c * 256;
    h_lds[idx >> 6][idx & 63] = hstate[(long)r0 * Hh + idx];
  }
  __syncthreads();
#pragma unroll
  for (int rep = 0; rep < 2; ++rep) {
    int idx = tid + rep * 256;
    int row = idx >> 5, m = idx & 31;
    float um = bm1[m];
    for (int k = 0; k < Hh; ++k) um += wm1T[k * M1 + m] * h_lds[row][k];
    u_lds[row][m] = fmaxf(um, 0.f);
  }
  __syncthreads();
  if (tid < RPB * Fp) {
    int row = tid / Fp, f = tid % Fp;
    float pf = bm2[f];
#pragma unroll
    for (int m = 0; m < M1; ++m) pf += wm2T[m * Fp + f] * u_lds[row][m];
    xnext[(r0 + row) * Fp + f] = pf;
  }
}

// ---------------------------------------------------------------------------
extern "C" void kernel_launch(void* const* d_in, const int* in_sizes, int n_in,
                              void* d_out, int out_size, void* d_ws, size_t ws_size,
                              hipStream_t stream) {
  const float* hp     = (const float*)d_in[0];
  const float* hw     = (const float*)d_in[1];
  const float* adj    = (const float*)d_in[2];
  const float* coords = (const float*)d_in[3];
  const float* wgc1   = (const float*)d_in[4];
  const float* bgc1   = (const float*)d_in[5];
  const float* wgc2   = (const float*)d_in[6];
  const float* bgc2   = (const float*)d_in[7];
  const float* wih    = (const float*)d_in[8];
  const float* whh    = (const float*)d_in[9];
  const float* bih    = (const float*)d_in[10];
  const float* bhh    = (const float*)d_in[11];
  const float* wm1    = (const float*)d_in[12];
  const float* bm1    = (const float*)d_in[13];
  const float* wm2    = (const float*)d_in[14];
  const float* bm2    = (const float*)d_in[15];
  float* out = (float*)d_out;

  float* w = (float*)d_ws;
  float* Ac     = w; w += Nn * Nn;
  float* As     = w; w += Nn * Nn;
  float* dbuf   = w; w += Tt * Bsz * Nn;
  float* ebuf   = w; w += Tt * Bsz * Nn;
  float* hstate = w; w += Bsz * Nn * Hh;
  float* h1_all = w; w += (long)Tt * Bsz * Nn * Hh;
  float* sf_all = w; w += (long)Tt * Bsz * Nn * Hh;
  float* h1d    = w; w += Bsz * Nn * Hh;
  float* xb     = w; w += Bsz * Nn * Fp;
  float* A1d    = w; w += Bsz * Nn * Nn;
  float* A2d    = w; w += Bsz * Nn * Nn;
  float* wgc2T  = w; w += Hh * Hh;
  float* wihT   = w; w += Hh * G3;
  float* whhT   = w; w += Hh * G3;
  float* wm1T   = w; w += Hh * M1;
  float* wm2T   = w; w += M1 * Fp;

  k_prep_ang<<<Nn, 256, 0, stream>>>(coords, adj, Ac, As);
  k_transpose_weights<<<1, 256, 0, stream>>>(wgc2, wih, whh, wm1, wm2,
                                             wgc2T, wihT, whhT, wm1T, wm2T);
  k_deg<<<Tt * Bsz * 4, 256, 0, stream>>>(hw, Ac, As, dbuf, ebuf);

  // encoder: fully batched over t
  k_gconv1_enc<<<Tt * Bsz * 16, 256, 0, stream>>>(hp, hw, Ac, As, dbuf,
                                                  wgc1, bgc1, h1_all);
  k_gconv2_enc<<<Tt * Bsz * 16, 256, 0, stream>>>(hw, Ac, As, ebuf, h1_all,
                                                  wgc2T, bgc2, sf_all);
  k_gru_scan<<<Bsz * 16, 256, 0, stream>>>(sf_all, wihT, whhT, bih, bhh, hstate);

  // decoder
  k_norm_dec<<<Bsz * Nn, 256, 0, stream>>>(hw, Ac, As, dbuf, ebuf, A1d, A2d);
  k_dec0<<<Bsz * Nn / 16, 256, 0, stream>>>(hstate, wm1T, bm1, wm2T, bm2, xb);

  for (int p = 0; p < PredL; ++p) {
    k_gconv1_dec<<<Bsz * 16, 256, 0, stream>>>(xb, A1d, wgc1, bgc1, h1d);
    k_gconv2_gru_dec<<<Bsz * 16, 256, 0, stream>>>(
        A2d, h1d, wgc2T, bgc2, wihT, whhT, bih, bhh, hstate,
        wm1T, bm1, wm2T, bm2, out, xb, p);
  }
}